// Round 1
// baseline (157.557 us; speedup 1.0000x reference)
//
#include <hip/hip_runtime.h>

#define NBATCH 2
#define NPTS   16384
#define JCH    8                 // j-chunks for parallelism
#define JLEN   (NPTS / JCH)      // 2048

// Pack (x,y,z) -> float4(x, y, z, 0.5*(x^2+y^2+z^2)) for both clouds.
__global__ __launch_bounds__(256) void pack_pts(
    const float* __restrict__ c1, const float* __restrict__ c2,
    float4* __restrict__ p1, float4* __restrict__ p2)
{
    int idx = blockIdx.x * 256 + threadIdx.x;      // 0 .. 2*NBATCH*NPTS
    const int total = NBATCH * NPTS;
    const float* __restrict__ src = (idx < total) ? c1 : c2;
    float4* __restrict__ dst = (idx < total) ? p1 : p2;
    int i = (idx < total) ? idx : idx - total;
    float x = src[3 * i + 0];
    float y = src[3 * i + 1];
    float z = src[3 * i + 2];
    dst[i] = make_float4(x, y, z, 0.5f * (x * x + y * y + z * z));
}

// For each a-point i (one per thread), min over a j-chunk of
//   t = 0.5*||b||^2 - a.b   ;  d2 = max(0, 2*tmin + ||a||^2)
// atomicMin on uint bits (d2 >= 0 so float bits are order-preserving).
__global__ __launch_bounds__(256) void chamfer_min(
    const float4* __restrict__ p1, const float4* __restrict__ p2,
    unsigned int* __restrict__ mins /* [2][NBATCH][NPTS] */)
{
    int bid = blockIdx.x;
    const int jc = bid & (JCH - 1); bid >>= 3;
    const int ab = bid & 63;        bid >>= 6;
    const int n  = bid & 1;         bid >>= 1;
    const int dir = bid;            // 0: a=cloud1,b=cloud2 ; 1: a=cloud2,b=cloud1

    const float4* __restrict__ pa = dir ? p2 : p1;
    const float4* __restrict__ pb = dir ? p1 : p2;

    const int i = ab * 256 + (int)threadIdx.x;
    const float4 a = pa[n * NPTS + i];
    const float nax = -a.x, nay = -a.y, naz = -a.z;
    const float sqa = 2.0f * a.w;

    const float4* __restrict__ bb = pb + n * NPTS + jc * JLEN;

    float tm0 = 3.0e38f, tm1 = 3.0e38f, tm2 = 3.0e38f, tm3 = 3.0e38f;
    #pragma unroll 4
    for (int j = 0; j < JLEN; j += 4) {
        float4 b0 = bb[j + 0];
        float4 b1 = bb[j + 1];
        float4 b2 = bb[j + 2];
        float4 b3 = bb[j + 3];
        tm0 = fminf(tm0, fmaf(nax, b0.x, fmaf(nay, b0.y, fmaf(naz, b0.z, b0.w))));
        tm1 = fminf(tm1, fmaf(nax, b1.x, fmaf(nay, b1.y, fmaf(naz, b1.z, b1.w))));
        tm2 = fminf(tm2, fmaf(nax, b2.x, fmaf(nay, b2.y, fmaf(naz, b2.z, b2.w))));
        tm3 = fminf(tm3, fmaf(nax, b3.x, fmaf(nay, b3.y, fmaf(naz, b3.z, b3.w))));
    }
    float tmin = fminf(fminf(tm0, tm1), fminf(tm2, tm3));
    float d2 = fmaxf(0.0f, fmaf(2.0f, tmin, sqa));
    atomicMin(&mins[(dir * NBATCH + n) * NPTS + i], __float_as_uint(d2));
}

// out[n] = mean_i min_a2b + mean_j min_b2a  (P1 == P2 so one divide).
__global__ __launch_bounds__(256) void chamfer_out(
    const unsigned int* __restrict__ mins, float* __restrict__ out)
{
    int n = blockIdx.x;
    float acc = 0.0f;
    for (int i = threadIdx.x; i < NPTS; i += 256) {
        acc += __uint_as_float(mins[(0 * NBATCH + n) * NPTS + i]);
        acc += __uint_as_float(mins[(1 * NBATCH + n) * NPTS + i]);
    }
    for (int off = 32; off > 0; off >>= 1) acc += __shfl_down(acc, off, 64);
    __shared__ float sm[4];
    int wv = threadIdx.x >> 6, ln = threadIdx.x & 63;
    if (ln == 0) sm[wv] = acc;
    __syncthreads();
    if (threadIdx.x == 0)
        out[n] = (sm[0] + sm[1] + sm[2] + sm[3]) / (float)NPTS;
}

extern "C" void kernel_launch(void* const* d_in, const int* in_sizes, int n_in,
                              void* d_out, int out_size, void* d_ws, size_t ws_size,
                              hipStream_t stream)
{
    const float* c1 = (const float*)d_in[0];
    const float* c2 = (const float*)d_in[1];
    float* out = (float*)d_out;

    char* ws = (char*)d_ws;
    float4* p1 = (float4*)ws;                                          // 512 KB
    float4* p2 = (float4*)(ws + (size_t)NBATCH * NPTS * sizeof(float4));
    unsigned int* mins = (unsigned int*)(ws + 2 * (size_t)NBATCH * NPTS * sizeof(float4)); // 256 KB

    // init mins to a huge positive float (0x7f7f7f7f both as uint and float)
    hipMemsetAsync(mins, 0x7F, (size_t)2 * NBATCH * NPTS * sizeof(unsigned int), stream);

    pack_pts<<<(2 * NBATCH * NPTS) / 256, 256, 0, stream>>>(c1, c2, p1, p2);
    chamfer_min<<<2 * NBATCH * 64 * JCH, 256, 0, stream>>>(p1, p2, mins);
    chamfer_out<<<NBATCH, 256, 0, stream>>>(mins, out);
}

// Round 2
// 130.546 us; speedup vs baseline: 1.2069x; 1.2069x over previous
//
#include <hip/hip_runtime.h>

#define NBATCH 2
#define NPTS   16384
#define JCH    32                // j-chunks per direction/batch
#define JLEN   (NPTS / JCH)      // 512
#define APT    4                 // a-points per thread
#define ABLK   (256 * APT)       // 1024 a-points per block
#define NAB    (NPTS / ABLK)     // 16 a-blocks

// Pack (x,y,z) -> float4(x, y, z, 0.5*(x^2+y^2+z^2)) for both clouds.
__global__ __launch_bounds__(256) void pack_pts(
    const float* __restrict__ c1, const float* __restrict__ c2,
    float4* __restrict__ p1, float4* __restrict__ p2)
{
    int idx = blockIdx.x * 256 + threadIdx.x;      // 0 .. 2*NBATCH*NPTS
    const int total = NBATCH * NPTS;
    const float* __restrict__ src = (idx < total) ? c1 : c2;
    float4* __restrict__ dst = (idx < total) ? p1 : p2;
    int i = (idx < total) ? idx : idx - total;
    float x = src[3 * i + 0];
    float y = src[3 * i + 1];
    float z = src[3 * i + 2];
    dst[i] = make_float4(x, y, z, 0.5f * (x * x + y * y + z * z));
}

// Each thread owns APT=4 a-points; loop over a j-chunk of b-points (scalarized
// wave-uniform s_load_dwordx4 stream). Per b-point: 1 v_mov + 4*(3 fma + 1 min)
// = 4.25 VALU/pair.  t = 0.5*||b||^2 - a.b ; d2 = max(0, 2*tmin + ||a||^2).
// atomicMin on uint bits (d2 >= 0 so float bits are order-preserving).
__global__ __launch_bounds__(256) void chamfer_min(
    const float4* __restrict__ p1, const float4* __restrict__ p2,
    unsigned int* __restrict__ mins /* [2][NBATCH][NPTS] */)
{
    int bid = blockIdx.x;
    const int jc = bid & (JCH - 1); bid >>= 5;
    const int ab = bid & (NAB - 1); bid >>= 4;
    const int n  = bid & 1;         bid >>= 1;
    const int dir = bid;            // 0: a=cloud1,b=cloud2 ; 1: a=cloud2,b=cloud1

    const float4* __restrict__ pa = dir ? p2 : p1;
    const float4* __restrict__ pb = dir ? p1 : p2;

    const int i0 = ab * ABLK + (int)threadIdx.x;

    float nax[APT], nay[APT], naz[APT], sqa[APT], tm[APT];
    #pragma unroll
    for (int k = 0; k < APT; ++k) {
        float4 a = pa[n * NPTS + i0 + k * 256];
        nax[k] = -a.x; nay[k] = -a.y; naz[k] = -a.z;
        sqa[k] = 2.0f * a.w;
        tm[k] = 3.0e38f;
    }

    const float4* __restrict__ bb = pb + n * NPTS + jc * JLEN;

    #pragma unroll 4
    for (int j = 0; j < JLEN; ++j) {
        float4 b = bb[j];
        #pragma unroll
        for (int k = 0; k < APT; ++k) {
            tm[k] = fminf(tm[k],
                fmaf(nax[k], b.x, fmaf(nay[k], b.y, fmaf(naz[k], b.z, b.w))));
        }
    }

    #pragma unroll
    for (int k = 0; k < APT; ++k) {
        float d2 = fmaxf(0.0f, fmaf(2.0f, tm[k], sqa[k]));
        atomicMin(&mins[(dir * NBATCH + n) * NPTS + i0 + k * 256],
                  __float_as_uint(d2));
    }
}

// out[n] = mean_i min_a2b + mean_j min_b2a  (P1 == P2 so one divide).
__global__ __launch_bounds__(256) void chamfer_out(
    const unsigned int* __restrict__ mins, float* __restrict__ out)
{
    int n = blockIdx.x;
    float acc = 0.0f;
    for (int i = threadIdx.x; i < NPTS; i += 256) {
        acc += __uint_as_float(mins[(0 * NBATCH + n) * NPTS + i]);
        acc += __uint_as_float(mins[(1 * NBATCH + n) * NPTS + i]);
    }
    for (int off = 32; off > 0; off >>= 1) acc += __shfl_down(acc, off, 64);
    __shared__ float sm[4];
    int wv = threadIdx.x >> 6, ln = threadIdx.x & 63;
    if (ln == 0) sm[wv] = acc;
    __syncthreads();
    if (threadIdx.x == 0)
        out[n] = (sm[0] + sm[1] + sm[2] + sm[3]) / (float)NPTS;
}

extern "C" void kernel_launch(void* const* d_in, const int* in_sizes, int n_in,
                              void* d_out, int out_size, void* d_ws, size_t ws_size,
                              hipStream_t stream)
{
    const float* c1 = (const float*)d_in[0];
    const float* c2 = (const float*)d_in[1];
    float* out = (float*)d_out;

    char* ws = (char*)d_ws;
    float4* p1 = (float4*)ws;                                          // 512 KB
    float4* p2 = (float4*)(ws + (size_t)NBATCH * NPTS * sizeof(float4));
    unsigned int* mins = (unsigned int*)(ws + 2 * (size_t)NBATCH * NPTS * sizeof(float4)); // 256 KB

    // init mins to a huge positive float (0x7f7f7f7f both as uint and float)
    hipMemsetAsync(mins, 0x7F, (size_t)2 * NBATCH * NPTS * sizeof(unsigned int), stream);

    pack_pts<<<(2 * NBATCH * NPTS) / 256, 256, 0, stream>>>(c1, c2, p1, p2);
    chamfer_min<<<2 * NBATCH * NAB * JCH, 256, 0, stream>>>(p1, p2, mins);
    chamfer_out<<<NBATCH, 256, 0, stream>>>(mins, out);
}

// Round 3
// 126.486 us; speedup vs baseline: 1.2456x; 1.0321x over previous
//
#include <hip/hip_runtime.h>

#define NBATCH 2
#define NPTS   16384
#define JCH    64                // j-chunks per direction/batch
#define JLEN   (NPTS / JCH)      // 256
#define APT    8                 // a-points per thread
#define ABLK   (256 * APT)       // 2048 a-points per block
#define NAB    (NPTS / ABLK)     // 8 a-blocks

// Pack (x,y,z) -> float4(x, y, z, 0.5*(x^2+y^2+z^2)) for both clouds.
__global__ __launch_bounds__(256) void pack_pts(
    const float* __restrict__ c1, const float* __restrict__ c2,
    float4* __restrict__ p1, float4* __restrict__ p2)
{
    int idx = blockIdx.x * 256 + threadIdx.x;      // 0 .. 2*NBATCH*NPTS
    const int total = NBATCH * NPTS;
    const float* __restrict__ src = (idx < total) ? c1 : c2;
    float4* __restrict__ dst = (idx < total) ? p1 : p2;
    int i = (idx < total) ? idx : idx - total;
    float x = src[3 * i + 0];
    float y = src[3 * i + 1];
    float z = src[3 * i + 2];
    dst[i] = make_float4(x, y, z, 0.5f * (x * x + y * y + z * z));
}

// Each thread owns APT=8 a-points; iterate b-points 2 at a time so the min
// fold maps to v_min3_f32: per 2 b-points: 48 v_fma + 8 v_min3 = 3.5 VALU/pair.
//   t = 0.5*||b||^2 - a.b ; d2 = max(0, 2*tmin + ||a||^2)
// atomicMin on uint bits (d2 >= 0 so float bits are order-preserving).
__global__ __launch_bounds__(256) void chamfer_min(
    const float4* __restrict__ p1, const float4* __restrict__ p2,
    unsigned int* __restrict__ mins /* [2][NBATCH][NPTS] */)
{
    int bid = blockIdx.x;
    const int jc = bid & (JCH - 1); bid >>= 6;
    const int ab = bid & (NAB - 1); bid >>= 3;
    const int n  = bid & 1;         bid >>= 1;
    const int dir = bid;            // 0: a=cloud1,b=cloud2 ; 1: a=cloud2,b=cloud1

    const float4* __restrict__ pa = dir ? p2 : p1;
    const float4* __restrict__ pb = dir ? p1 : p2;

    const int i0 = ab * ABLK + (int)threadIdx.x;

    float nax[APT], nay[APT], naz[APT], sqa[APT], tm[APT];
    #pragma unroll
    for (int k = 0; k < APT; ++k) {
        float4 a = pa[n * NPTS + i0 + k * 256];
        nax[k] = -a.x; nay[k] = -a.y; naz[k] = -a.z;
        sqa[k] = 2.0f * a.w;
        tm[k] = 3.0e38f;
    }

    const float4* __restrict__ bb = pb + n * NPTS + jc * JLEN;

    #pragma unroll 2
    for (int j = 0; j < JLEN; j += 2) {
        float4 b0 = bb[j + 0];
        float4 b1 = bb[j + 1];
        #pragma unroll
        for (int k = 0; k < APT; ++k) {
            float t0 = fmaf(nax[k], b0.x, fmaf(nay[k], b0.y, fmaf(naz[k], b0.z, b0.w)));
            float t1 = fmaf(nax[k], b1.x, fmaf(nay[k], b1.y, fmaf(naz[k], b1.z, b1.w)));
            tm[k] = fminf(fminf(tm[k], t0), t1);   // -> v_min3_f32
        }
    }

    #pragma unroll
    for (int k = 0; k < APT; ++k) {
        float d2 = fmaxf(0.0f, fmaf(2.0f, tm[k], sqa[k]));
        atomicMin(&mins[(dir * NBATCH + n) * NPTS + i0 + k * 256],
                  __float_as_uint(d2));
    }
}

// out[n] = mean_i min_a2b + mean_j min_b2a  (P1 == P2 so one divide).
__global__ __launch_bounds__(256) void chamfer_out(
    const unsigned int* __restrict__ mins, float* __restrict__ out)
{
    int n = blockIdx.x;
    float acc = 0.0f;
    for (int i = threadIdx.x; i < NPTS; i += 256) {
        acc += __uint_as_float(mins[(0 * NBATCH + n) * NPTS + i]);
        acc += __uint_as_float(mins[(1 * NBATCH + n) * NPTS + i]);
    }
    for (int off = 32; off > 0; off >>= 1) acc += __shfl_down(acc, off, 64);
    __shared__ float sm[4];
    int wv = threadIdx.x >> 6, ln = threadIdx.x & 63;
    if (ln == 0) sm[wv] = acc;
    __syncthreads();
    if (threadIdx.x == 0)
        out[n] = (sm[0] + sm[1] + sm[2] + sm[3]) / (float)NPTS;
}

extern "C" void kernel_launch(void* const* d_in, const int* in_sizes, int n_in,
                              void* d_out, int out_size, void* d_ws, size_t ws_size,
                              hipStream_t stream)
{
    const float* c1 = (const float*)d_in[0];
    const float* c2 = (const float*)d_in[1];
    float* out = (float*)d_out;

    char* ws = (char*)d_ws;
    float4* p1 = (float4*)ws;                                          // 512 KB
    float4* p2 = (float4*)(ws + (size_t)NBATCH * NPTS * sizeof(float4));
    unsigned int* mins = (unsigned int*)(ws + 2 * (size_t)NBATCH * NPTS * sizeof(float4)); // 256 KB

    // init mins to a huge positive float (0x7f7f7f7f both as uint and float)
    hipMemsetAsync(mins, 0x7F, (size_t)2 * NBATCH * NPTS * sizeof(unsigned int), stream);

    pack_pts<<<(2 * NBATCH * NPTS) / 256, 256, 0, stream>>>(c1, c2, p1, p2);
    chamfer_min<<<2 * NBATCH * NAB * JCH, 256, 0, stream>>>(p1, p2, mins);
    chamfer_out<<<NBATCH, 256, 0, stream>>>(mins, out);
}

// Round 4
// 125.756 us; speedup vs baseline: 1.2529x; 1.0058x over previous
//
#include <hip/hip_runtime.h>

#define NBATCH 2
#define NPTS   16384
#define JCH    64                // j-chunks per direction/batch
#define JLEN   (NPTS / JCH)      // 256
#define APT    8                 // a-points per thread
#define ABLK   (256 * APT)       // 2048 a-points per block
#define NAB    (NPTS / ABLK)     // 8 a-blocks

// Pack (x,y,z) -> float4(x, y, z, 0.5*(x^2+y^2+z^2)) for both clouds.
__global__ __launch_bounds__(256) void pack_pts(
    const float* __restrict__ c1, const float* __restrict__ c2,
    float4* __restrict__ p1, float4* __restrict__ p2)
{
    int idx = blockIdx.x * 256 + threadIdx.x;      // 0 .. 2*NBATCH*NPTS
    const int total = NBATCH * NPTS;
    const float* __restrict__ src = (idx < total) ? c1 : c2;
    float4* __restrict__ dst = (idx < total) ? p1 : p2;
    int i = (idx < total) ? idx : idx - total;
    float x = src[3 * i + 0];
    float y = src[3 * i + 1];
    float z = src[3 * i + 2];
    dst[i] = make_float4(x, y, z, 0.5f * (x * x + y * y + z * z));
}

// v_min3_f32 via inline asm: guarantees 1 instruction per 2-pair min fold,
// bypassing any canonicalize insertion / failed min3 pattern-match.
// All values are finite (random normal inputs), so min3 == fminf chain.
__device__ __forceinline__ void min3_fold(float& tm, float t0, float t1) {
    asm("v_min3_f32 %0, %1, %2, %3" : "=v"(tm) : "v"(tm), "v"(t0), "v"(t1));
}

// Each thread owns APT=8 a-points; 4 b-points per iteration.
// Per 4 b-points per k: 12 v_fma + 2 v_min3 -> 3.5 VALU/pair core.
//   t = 0.5*||b||^2 - a.b ; d2 = max(0, 2*tmin + ||a||^2)
// atomicMin on uint bits (d2 >= 0 so float bits are order-preserving).
__global__ __launch_bounds__(256) void chamfer_min(
    const float4* __restrict__ p1, const float4* __restrict__ p2,
    unsigned int* __restrict__ mins /* [2][NBATCH][NPTS] */)
{
    int bid = blockIdx.x;
    const int jc = bid & (JCH - 1); bid >>= 6;
    const int ab = bid & (NAB - 1); bid >>= 3;
    const int n  = bid & 1;         bid >>= 1;
    const int dir = bid;            // 0: a=cloud1,b=cloud2 ; 1: a=cloud2,b=cloud1

    const float4* __restrict__ pa = dir ? p2 : p1;
    const float4* __restrict__ pb = dir ? p1 : p2;

    const int i0 = ab * ABLK + (int)threadIdx.x;

    float nax[APT], nay[APT], naz[APT], sqa[APT], tm[APT];
    #pragma unroll
    for (int k = 0; k < APT; ++k) {
        float4 a = pa[n * NPTS + i0 + k * 256];
        nax[k] = -a.x; nay[k] = -a.y; naz[k] = -a.z;
        sqa[k] = 2.0f * a.w;
        tm[k] = 3.0e38f;
    }

    const float4* __restrict__ bb = pb + n * NPTS + jc * JLEN;

    for (int j = 0; j < JLEN; j += 4) {
        float4 b0 = bb[j + 0];
        float4 b1 = bb[j + 1];
        float4 b2 = bb[j + 2];
        float4 b3 = bb[j + 3];
        #pragma unroll
        for (int k = 0; k < APT; ++k) {
            float t0 = fmaf(nax[k], b0.x, fmaf(nay[k], b0.y, fmaf(naz[k], b0.z, b0.w)));
            float t1 = fmaf(nax[k], b1.x, fmaf(nay[k], b1.y, fmaf(naz[k], b1.z, b1.w)));
            float t2 = fmaf(nax[k], b2.x, fmaf(nay[k], b2.y, fmaf(naz[k], b2.z, b2.w)));
            float t3 = fmaf(nax[k], b3.x, fmaf(nay[k], b3.y, fmaf(naz[k], b3.z, b3.w)));
            min3_fold(tm[k], t0, t1);
            min3_fold(tm[k], t2, t3);
        }
    }

    #pragma unroll
    for (int k = 0; k < APT; ++k) {
        float d2 = fmaxf(0.0f, fmaf(2.0f, tm[k], sqa[k]));
        atomicMin(&mins[(dir * NBATCH + n) * NPTS + i0 + k * 256],
                  __float_as_uint(d2));
    }
}

// out[n] = mean_i min_a2b + mean_j min_b2a  (P1 == P2 so one divide).
__global__ __launch_bounds__(256) void chamfer_out(
    const unsigned int* __restrict__ mins, float* __restrict__ out)
{
    int n = blockIdx.x;
    float acc = 0.0f;
    for (int i = threadIdx.x; i < NPTS; i += 256) {
        acc += __uint_as_float(mins[(0 * NBATCH + n) * NPTS + i]);
        acc += __uint_as_float(mins[(1 * NBATCH + n) * NPTS + i]);
    }
    for (int off = 32; off > 0; off >>= 1) acc += __shfl_down(acc, off, 64);
    __shared__ float sm[4];
    int wv = threadIdx.x >> 6, ln = threadIdx.x & 63;
    if (ln == 0) sm[wv] = acc;
    __syncthreads();
    if (threadIdx.x == 0)
        out[n] = (sm[0] + sm[1] + sm[2] + sm[3]) / (float)NPTS;
}

extern "C" void kernel_launch(void* const* d_in, const int* in_sizes, int n_in,
                              void* d_out, int out_size, void* d_ws, size_t ws_size,
                              hipStream_t stream)
{
    const float* c1 = (const float*)d_in[0];
    const float* c2 = (const float*)d_in[1];
    float* out = (float*)d_out;

    char* ws = (char*)d_ws;
    float4* p1 = (float4*)ws;                                          // 512 KB
    float4* p2 = (float4*)(ws + (size_t)NBATCH * NPTS * sizeof(float4));
    unsigned int* mins = (unsigned int*)(ws + 2 * (size_t)NBATCH * NPTS * sizeof(float4)); // 256 KB

    // init mins to a huge positive float (0x7f7f7f7f both as uint and float)
    hipMemsetAsync(mins, 0x7F, (size_t)2 * NBATCH * NPTS * sizeof(unsigned int), stream);

    pack_pts<<<(2 * NBATCH * NPTS) / 256, 256, 0, stream>>>(c1, c2, p1, p2);
    chamfer_min<<<2 * NBATCH * NAB * JCH, 256, 0, stream>>>(p1, p2, mins);
    chamfer_out<<<NBATCH, 256, 0, stream>>>(mins, out);
}